// Round 1
// baseline (85.935 us; speedup 1.0000x reference)
//
#include <hip/hip_runtime.h>

// Problem constants (fixed by setup_inputs): B=4, S=256, D=512, P=256
constexpr int B = 4;
constexpr int S = 256;
constexpr int D = 512;
constexpr int P = 256;
constexpr float NEG_INF = -1e9f;
constexpr float LOG2E = 1.4426950408889634f;

__device__ __forceinline__ float fast_exp2(float x) {
#if __has_builtin(__builtin_amdgcn_exp2f)
    return __builtin_amdgcn_exp2f(x);
#else
    return exp2f(x);
#endif
}

__device__ __forceinline__ float fast_rcp(float x) {
#if __has_builtin(__builtin_amdgcn_rcpf)
    return __builtin_amdgcn_rcpf(x);
#else
    return 1.0f / x;
#endif
}

// tanh(x) = (e^{2x}-1)/(e^{2x}+1); exp2-based, 1 exp + 1 rcp
__device__ __forceinline__ float tanh_fast(float x) {
    x = fminf(fmaxf(x, -30.f), 30.f);           // keep exp2 arg in range
    float t = fast_exp2(x * 2.885390081777927f); // 2*log2(e)
    return (t - 1.f) * fast_rcp(t + 1.f);
}

// ---------------------------------------------------------------------------
// K1: pk = seq @ W1^T, pq = seq @ W2^T
// grid = B * (S/8) * 2 = 256 blocks, 256 threads (thread = p)
// ---------------------------------------------------------------------------
__global__ __launch_bounds__(256)
void proj_kernel(const float* __restrict__ seq,
                 const float* __restrict__ W1, const float* __restrict__ W2,
                 float* __restrict__ pk, float* __restrict__ pq) {
    __shared__ float sq[8 * D]; // 16 KiB seq tile
    int bid = blockIdx.x;
    int which = bid & 1;
    int r = bid >> 1;
    int b = r >> 5;
    int s0 = (r & 31) * 8;
    const float* W = which ? W2 : W1;
    float* out = which ? pq : pk;
    int tid = threadIdx.x;

    // stage 8 seq rows (4096 floats = 1024 float4), coalesced
    const float4* src = (const float4*)(seq + (size_t)(b * S + s0) * D);
    float4* dst = (float4*)sq;
#pragma unroll
    for (int k = 0; k < 4; k++) dst[tid + k * 256] = src[tid + k * 256];
    __syncthreads();

    int p = tid;
    const float* wrow = W + (size_t)p * D;
    float acc[8] = {0.f, 0.f, 0.f, 0.f, 0.f, 0.f, 0.f, 0.f};
    for (int d0 = 0; d0 < D; d0 += 4) {
        float4 w4 = *(const float4*)(wrow + d0);
#pragma unroll
        for (int s = 0; s < 8; s++) {
            float4 q4 = *(const float4*)(&sq[s * D + d0]);
            acc[s] = fmaf(w4.x, q4.x, acc[s]);
            acc[s] = fmaf(w4.y, q4.y, acc[s]);
            acc[s] = fmaf(w4.z, q4.z, acc[s]);
            acc[s] = fmaf(w4.w, q4.w, acc[s]);
        }
    }
#pragma unroll
    for (int s = 0; s < 8; s++)
        out[(size_t)(b * S + s0 + s) * P + p] = acc[s];
}

// ---------------------------------------------------------------------------
// K2: scores + masked softmax -> weights (written to d_out weights region,
//     already multiplied by the query mask)
// grid = B * (S/4) = 256 blocks, 256 threads (thread = key j)
// ---------------------------------------------------------------------------
__global__ __launch_bounds__(256)
void score_kernel(const float* __restrict__ pk, const float* __restrict__ pq,
                  const float* __restrict__ v, const float* __restrict__ mask,
                  float* __restrict__ wout) {
    __shared__ float pqs[4][P]; // 4 KiB
    __shared__ float vs[P];     // 1 KiB
    __shared__ float rbm[4][4], rbs[4][4];
    int bid = blockIdx.x;
    int b = bid >> 6;
    int i0 = (bid & 63) * 4;
    int tid = threadIdx.x;
    int lane = tid & 63;
    int wid = tid >> 6;

    vs[tid] = v[tid];
#pragma unroll
    for (int q = 0; q < 4; q++)
        pqs[q][tid] = pq[(size_t)(b * S + i0 + q) * P + tid];
    __syncthreads();

    int j = tid;
    const float* pkrow = pk + (size_t)(b * S + j) * P;
    float acc[4] = {0.f, 0.f, 0.f, 0.f};
    for (int p0 = 0; p0 < P; p0 += 4) {
        float4 k4 = *(const float4*)(pkrow + p0);
        float4 v4 = *(const float4*)(&vs[p0]);
#pragma unroll
        for (int q = 0; q < 4; q++) {
            float4 q4 = *(const float4*)(&pqs[q][p0]);
            acc[q] = fmaf(v4.x, tanh_fast(k4.x + q4.x), acc[q]);
            acc[q] = fmaf(v4.y, tanh_fast(k4.y + q4.y), acc[q]);
            acc[q] = fmaf(v4.z, tanh_fast(k4.z + q4.z), acc[q]);
            acc[q] = fmaf(v4.w, tanh_fast(k4.w + q4.w), acc[q]);
        }
    }

    float kmask = mask[b * S + j];
    float sc[4];
#pragma unroll
    for (int q = 0; q < 4; q++) sc[q] = (kmask > 0.f) ? acc[q] : NEG_INF;

    // block softmax over the 256 j-threads (per query row)
#pragma unroll
    for (int q = 0; q < 4; q++) {
        float mm = sc[q];
#pragma unroll
        for (int off = 32; off >= 1; off >>= 1)
            mm = fmaxf(mm, __shfl_xor(mm, off, 64));
        if (lane == 0) rbm[q][wid] = mm;
    }
    __syncthreads();

    float e[4];
#pragma unroll
    for (int q = 0; q < 4; q++) {
        float mm = fmaxf(fmaxf(rbm[q][0], rbm[q][1]), fmaxf(rbm[q][2], rbm[q][3]));
        float ee = fast_exp2((sc[q] - mm) * LOG2E);
        e[q] = ee;
        float ss = ee;
#pragma unroll
        for (int off = 32; off >= 1; off >>= 1)
            ss += __shfl_xor(ss, off, 64);
        if (lane == 0) rbs[q][wid] = ss;
    }
    __syncthreads();

#pragma unroll
    for (int q = 0; q < 4; q++) {
        float ssum = rbs[q][0] + rbs[q][1] + rbs[q][2] + rbs[q][3];
        float qm = mask[b * S + i0 + q];
        float w = e[q] * fast_rcp(ssum) * qm;
        wout[(size_t)(b * S + i0 + q) * S + j] = w;
    }
}

// ---------------------------------------------------------------------------
// K3: attn[b,i,:] = weights[b,i,:] @ seq[b]   (weights already query-masked)
// grid = B * (S/4) = 256 blocks, 256 threads (thread = 2 d columns)
// ---------------------------------------------------------------------------
__global__ __launch_bounds__(256)
void attn_kernel(const float* __restrict__ seq, const float* __restrict__ wts,
                 float* __restrict__ attn) {
    __shared__ float ws_[4][S]; // 4 KiB
    int bid = blockIdx.x;
    int b = bid >> 6;
    int i0 = (bid & 63) * 4;
    int tid = threadIdx.x;
#pragma unroll
    for (int q = 0; q < 4; q++)
        ws_[q][tid] = wts[(size_t)(b * S + i0 + q) * S + tid];
    __syncthreads();

    int d0 = tid * 2;
    float2 acc[4] = {{0.f, 0.f}, {0.f, 0.f}, {0.f, 0.f}, {0.f, 0.f}};
    const float* sb = seq + (size_t)b * S * D + d0;
    for (int jj = 0; jj < S; jj++) {
        float2 s2 = *(const float2*)(sb + (size_t)jj * D);
#pragma unroll
        for (int q = 0; q < 4; q++) {
            float wv = ws_[q][jj];
            acc[q].x = fmaf(wv, s2.x, acc[q].x);
            acc[q].y = fmaf(wv, s2.y, acc[q].y);
        }
    }
#pragma unroll
    for (int q = 0; q < 4; q++)
        *(float2*)(attn + (size_t)(b * S + i0 + q) * D + d0) = acc[q];
}

// ---------------------------------------------------------------------------
extern "C" void kernel_launch(void* const* d_in, const int* in_sizes, int n_in,
                              void* d_out, int out_size, void* d_ws, size_t ws_size,
                              hipStream_t stream) {
    const float* seq  = (const float*)d_in[0];
    const float* mask = (const float*)d_in[1];
    const float* W1   = (const float*)d_in[2];
    const float* W2   = (const float*)d_in[3];
    const float* v    = (const float*)d_in[4];

    float* attn = (float*)d_out;                 // [B,S,D] = 524288 floats
    float* wout = attn + (size_t)B * S * D;      // [B,S,S] = 262144 floats

    float* pk = (float*)d_ws;                    // [B,S,P]
    float* pq = pk + (size_t)B * S * P;          // [B,S,P]

    proj_kernel<<<B * (S / 8) * 2, 256, 0, stream>>>(seq, W1, W2, pk, pq);
    score_kernel<<<B * (S / 4), 256, 0, stream>>>(pk, pq, v, mask, wout);
    attn_kernel<<<B * (S / 4), 256, 0, stream>>>(seq, wout, attn);
}

// Round 2
// 52.868 us; speedup vs baseline: 1.6255x; 1.6255x over previous
//
#include <hip/hip_runtime.h>

// Problem constants (fixed by setup_inputs): B=4, S=256, D=512, P=256
constexpr int B = 4;
constexpr int S = 256;
constexpr int D = 512;
constexpr int P = 256;
constexpr float NEG_INF = -1e9f;
constexpr float LOG2E = 1.4426950408889634f;

__device__ __forceinline__ float fast_exp2(float x) {
#if __has_builtin(__builtin_amdgcn_exp2f)
    return __builtin_amdgcn_exp2f(x);
#else
    return exp2f(x);
#endif
}

__device__ __forceinline__ float fast_rcp(float x) {
#if __has_builtin(__builtin_amdgcn_rcpf)
    return __builtin_amdgcn_rcpf(x);
#else
    return 1.0f / x;
#endif
}

// tanh(x) = 1 - 2/(e^{2x}+1).  No clamp needed: x->+inf => t=inf => rcp=0 => 1;
// x->-inf => t=0 => 1-2 = -1.  5 VALU + exp2 + rcp.
__device__ __forceinline__ float tanh_fast(float x) {
    float t = fast_exp2(x * 2.885390081777927f); // 2*log2(e)
    return fmaf(-2.f, fast_rcp(t + 1.f), 1.f);
}

// ---------------------------------------------------------------------------
// K1: pk = seq @ W1^T, pq = seq @ W2^T   (M=1024, N=256, K=512, x2 matrices)
// Tiled GEMM: block tile 32m x 64n, K-tile 64, thread tile 2m x 4n.
// grid = 32 mt * 4 nt * 2 which = 256 blocks, 256 threads.
// LDS transposed: As[k][m], Ws[k][n] -> vector reads, broadcast-friendly.
// ---------------------------------------------------------------------------
__global__ __launch_bounds__(256)
void proj_kernel(const float* __restrict__ seq,
                 const float* __restrict__ W1, const float* __restrict__ W2,
                 float* __restrict__ pk, float* __restrict__ pq) {
    __shared__ float As[64][34]; // [k][m], pad 2 (8B-aligned rows)
    __shared__ float Ws[64][68]; // [k][n], pad 4 (16B-aligned rows)

    int bid = blockIdx.x;
    int nt = bid & 3;
    int which = (bid >> 2) & 1;
    int mt = bid >> 3;
    int m0 = mt * 32;
    int p0 = nt * 64;
    const float* W = which ? W2 : W1;
    float* out = which ? pq : pk;
    int tid = threadIdx.x;
    int tx = tid & 15;  // n-group: cols 4*tx..+3
    int ty = tid >> 4;  // m-group: rows 2*ty..+1

    float c0[4] = {0.f, 0.f, 0.f, 0.f};
    float c1[4] = {0.f, 0.f, 0.f, 0.f};

    for (int kt = 0; kt < D; kt += 64) {
        // stage A tile: 32 rows x 64 k  (8 floats/thread)
        {
            int r = tid >> 3, cg = tid & 7;
            const float* src = seq + (size_t)(m0 + r) * D + kt + cg * 8;
            float4 g0 = *(const float4*)src;
            float4 g1 = *(const float4*)(src + 4);
            int kk = cg * 8;
            As[kk + 0][r] = g0.x; As[kk + 1][r] = g0.y;
            As[kk + 2][r] = g0.z; As[kk + 3][r] = g0.w;
            As[kk + 4][r] = g1.x; As[kk + 5][r] = g1.y;
            As[kk + 6][r] = g1.z; As[kk + 7][r] = g1.w;
        }
        // stage W tile: 64 rows x 64 k  (16 floats/thread)
        {
            int r = tid >> 2, cg = tid & 3;
            const float* src = W + (size_t)(p0 + r) * D + kt + cg * 16;
            float4 g0 = *(const float4*)(src);
            float4 g1 = *(const float4*)(src + 4);
            float4 g2 = *(const float4*)(src + 8);
            float4 g3 = *(const float4*)(src + 12);
            int kk = cg * 16;
            Ws[kk + 0][r] = g0.x;  Ws[kk + 1][r] = g0.y;
            Ws[kk + 2][r] = g0.z;  Ws[kk + 3][r] = g0.w;
            Ws[kk + 4][r] = g1.x;  Ws[kk + 5][r] = g1.y;
            Ws[kk + 6][r] = g1.z;  Ws[kk + 7][r] = g1.w;
            Ws[kk + 8][r] = g2.x;  Ws[kk + 9][r] = g2.y;
            Ws[kk + 10][r] = g2.z; Ws[kk + 11][r] = g2.w;
            Ws[kk + 12][r] = g3.x; Ws[kk + 13][r] = g3.y;
            Ws[kk + 14][r] = g3.z; Ws[kk + 15][r] = g3.w;
        }
        __syncthreads();
#pragma unroll 8
        for (int k = 0; k < 64; k++) {
            float2 a2 = *(const float2*)&As[k][ty * 2];
            float4 w4 = *(const float4*)&Ws[k][tx * 4];
            c0[0] = fmaf(a2.x, w4.x, c0[0]);
            c0[1] = fmaf(a2.x, w4.y, c0[1]);
            c0[2] = fmaf(a2.x, w4.z, c0[2]);
            c0[3] = fmaf(a2.x, w4.w, c0[3]);
            c1[0] = fmaf(a2.y, w4.x, c1[0]);
            c1[1] = fmaf(a2.y, w4.y, c1[1]);
            c1[2] = fmaf(a2.y, w4.z, c1[2]);
            c1[3] = fmaf(a2.y, w4.w, c1[3]);
        }
        __syncthreads();
    }
    {
        float4 o0 = {c0[0], c0[1], c0[2], c0[3]};
        float4 o1 = {c1[0], c1[1], c1[2], c1[3]};
        *(float4*)&out[(size_t)(m0 + ty * 2 + 0) * P + p0 + tx * 4] = o0;
        *(float4*)&out[(size_t)(m0 + ty * 2 + 1) * P + p0 + tx * 4] = o1;
    }
}

// ---------------------------------------------------------------------------
// K2: fused scores + masked softmax + attn for a 4-query tile.
// grid = B * (S/4) = 256 blocks, 512 threads (8 waves/CU).
// Phase 1: thread = (key j, p-half h): partial score over 128 p.
// Phase 2: threads 0..255 combine + softmax; weights -> LDS [j][q] + d_out.
// Phase 3: thread = d column: attn = w @ seq, coalesced.
// ---------------------------------------------------------------------------
__global__ __launch_bounds__(512)
void score_attn_kernel(const float* __restrict__ seq,
                       const float* __restrict__ pk, const float* __restrict__ pq,
                       const float* __restrict__ v, const float* __restrict__ mask,
                       float* __restrict__ wout, float* __restrict__ attn) {
    __shared__ float pqs[4][P];    // 4 KB  (4 query rows)
    __shared__ float vs[P];        // 1 KB
    __shared__ float part[4][S];   // 4 KB  (h=1 partials)
    __shared__ float wsm[S][4];    // 4 KB  (weights, [j][q] for b128 reads)
    __shared__ float redm[4][4], reds[4][4];

    int bid = blockIdx.x;
    int b = bid >> 6;
    int i0 = (bid & 63) * 4;
    int tid = threadIdx.x;
    int j = tid & 255;
    int h = tid >> 8;
    int lane = tid & 63;
    int wid = tid >> 6; // 0..3 for tid<256

    // stage pq rows (contiguous 1024 floats) and v
    {
        const float2* src = (const float2*)(pq + (size_t)(b * S + i0) * P);
        ((float2*)pqs)[tid] = src[tid];
        if (tid < 128) ((float2*)vs)[tid] = ((const float2*)v)[tid];
    }
    __syncthreads();

    // phase 1: partial scores over this thread's p-half
    float acc[4] = {0.f, 0.f, 0.f, 0.f};
    {
        const float* pkrow = pk + (size_t)(b * S + j) * P + h * 128;
        const int pb = h * 128;
#pragma unroll 4
        for (int p0 = 0; p0 < 128; p0 += 4) {
            float4 k4 = *(const float4*)(pkrow + p0);
            float4 v4 = *(const float4*)(&vs[pb + p0]);
#pragma unroll
            for (int q = 0; q < 4; q++) {
                float4 q4 = *(const float4*)(&pqs[q][pb + p0]);
                acc[q] = fmaf(v4.x, tanh_fast(k4.x + q4.x), acc[q]);
                acc[q] = fmaf(v4.y, tanh_fast(k4.y + q4.y), acc[q]);
                acc[q] = fmaf(v4.z, tanh_fast(k4.z + q4.z), acc[q]);
                acc[q] = fmaf(v4.w, tanh_fast(k4.w + q4.w), acc[q]);
            }
        }
    }
    if (h == 1) {
#pragma unroll
        for (int q = 0; q < 4; q++) part[q][j] = acc[q];
    }
    __syncthreads();

    // phase 2: softmax among threads 0..255 (thread = key j)
    float sc[4], e[4];
    if (tid < 256) {
        float kmask = mask[b * S + j];
#pragma unroll
        for (int q = 0; q < 4; q++) {
            float s = acc[q] + part[q][j];
            sc[q] = (kmask > 0.f) ? s : NEG_INF;
            float mm = sc[q];
#pragma unroll
            for (int off = 32; off >= 1; off >>= 1)
                mm = fmaxf(mm, __shfl_xor(mm, off, 64));
            if (lane == 0) redm[q][wid] = mm;
        }
    }
    __syncthreads();
    if (tid < 256) {
#pragma unroll
        for (int q = 0; q < 4; q++) {
            float mm = fmaxf(fmaxf(redm[q][0], redm[q][1]),
                             fmaxf(redm[q][2], redm[q][3]));
            float ee = fast_exp2((sc[q] - mm) * LOG2E);
            e[q] = ee;
            float ss = ee;
#pragma unroll
            for (int off = 32; off >= 1; off >>= 1)
                ss += __shfl_xor(ss, off, 64);
            if (lane == 0) reds[q][wid] = ss;
        }
    }
    __syncthreads();
    if (tid < 256) {
#pragma unroll
        for (int q = 0; q < 4; q++) {
            float ssum = reds[q][0] + reds[q][1] + reds[q][2] + reds[q][3];
            float qm = mask[b * S + i0 + q];
            float w = e[q] * fast_rcp(ssum) * qm;
            wsm[j][q] = w;
            wout[(size_t)(b * S + i0 + q) * S + j] = w;
        }
    }
    __syncthreads();

    // phase 3: attn[b, i0+q, d] = sum_j w[j][q] * seq[b, j, d]; thread = d
    {
        int d = tid; // 0..511
        float a0 = 0.f, a1 = 0.f, a2 = 0.f, a3 = 0.f;
        const float* sb = seq + (size_t)b * S * D + d;
#pragma unroll 4
        for (int jj = 0; jj < S; jj++) {
            float sv = sb[(size_t)jj * D];
            float4 w4 = *(const float4*)&wsm[jj][0];
            a0 = fmaf(w4.x, sv, a0);
            a1 = fmaf(w4.y, sv, a1);
            a2 = fmaf(w4.z, sv, a2);
            a3 = fmaf(w4.w, sv, a3);
        }
        attn[(size_t)(b * S + i0 + 0) * D + d] = a0;
        attn[(size_t)(b * S + i0 + 1) * D + d] = a1;
        attn[(size_t)(b * S + i0 + 2) * D + d] = a2;
        attn[(size_t)(b * S + i0 + 3) * D + d] = a3;
    }
}

// ---------------------------------------------------------------------------
extern "C" void kernel_launch(void* const* d_in, const int* in_sizes, int n_in,
                              void* d_out, int out_size, void* d_ws, size_t ws_size,
                              hipStream_t stream) {
    const float* seq  = (const float*)d_in[0];
    const float* mask = (const float*)d_in[1];
    const float* W1   = (const float*)d_in[2];
    const float* W2   = (const float*)d_in[3];
    const float* v    = (const float*)d_in[4];

    float* attn = (float*)d_out;                 // [B,S,D]
    float* wout = attn + (size_t)B * S * D;      // [B,S,S]

    float* pk = (float*)d_ws;                    // [B,S,P]
    float* pq = pk + (size_t)B * S * P;          // [B,S,P]

    proj_kernel<<<256, 256, 0, stream>>>(seq, W1, W2, pk, pq);
    score_attn_kernel<<<B * (S / 4), 512, 0, stream>>>(seq, pk, pq, v, mask,
                                                       wout, attn);
}

// Round 3
// 44.187 us; speedup vs baseline: 1.9448x; 1.1965x over previous
//
#include <hip/hip_runtime.h>

// Problem constants (fixed by setup_inputs): B=4, S=256, D=512, P=256
constexpr int B = 4;
constexpr int S = 256;
constexpr int D = 512;
constexpr int P = 256;
constexpr float NEG_INF = -1e9f;
constexpr float LOG2E = 1.4426950408889634f;
constexpr float C2 = 2.885390081777927f; // 2*log2(e):  exp2(C2*x) = e^{2x}

__device__ __forceinline__ float fast_exp2(float x) {
#if __has_builtin(__builtin_amdgcn_exp2f)
    return __builtin_amdgcn_exp2f(x);
#else
    return exp2f(x);
#endif
}

__device__ __forceinline__ float fast_rcp(float x) {
#if __has_builtin(__builtin_amdgcn_rcpf)
    return __builtin_amdgcn_rcpf(x);
#else
    return 1.0f / x;
#endif
}

// ---------------------------------------------------------------------------
// proj: out[m][n] = C2 * sum_k A[m][k] * Brows[n][k]
//   bid <  128 : pq  tiles  (A = seq rows, Brows = W2, out row-stride 256)
//   bid >= 128 : pkT tiles  (A = W1 rows,  Brows = seq[b], out row-stride 256)
// tile 32m x 64n, K-tile 64, 256 threads, thread-tile 2m x 4n, reg prefetch.
// ---------------------------------------------------------------------------
__global__ __launch_bounds__(256)
void proj_kernel(const float* __restrict__ seq,
                 const float* __restrict__ W1, const float* __restrict__ W2,
                 float* __restrict__ pq, float* __restrict__ pkT) {
    __shared__ float As[64][34]; // [k][m]
    __shared__ float Ws[64][68]; // [k][n]

    int bid0 = blockIdx.x;
    int bid = (bid0 & 7) * 32 + (bid0 >> 3); // XCD-aware swizzle (256 = 8*32)

    const float* A;
    const float* Bp;
    float* out;
    if (bid < 128) { // pq
        int mt = bid >> 2, nt = bid & 3;
        A = seq + (size_t)mt * 32 * D;
        Bp = W2 + (size_t)nt * 64 * D;
        out = pq + (size_t)mt * 32 * 256 + nt * 64;
    } else {         // pkT
        int r = bid - 128;
        int b = r >> 5, t = r & 31;
        int mt = t >> 2, nt = t & 3;
        A = W1 + (size_t)mt * 32 * D;
        Bp = seq + ((size_t)b * S + nt * 64) * D;
        out = pkT + (size_t)b * P * S + (size_t)mt * 32 * 256 + nt * 64;
    }

    int tid = threadIdx.x;
    int tx = tid & 15, ty = tid >> 4;
    int ar = tid >> 3, acg = tid & 7;   // A stage: row, 8-float chunk
    int br = tid >> 2, bcg = tid & 3;   // B stage: row, 16-float chunk
    const float* aptr = A + (size_t)ar * D + acg * 8;
    const float* bptr = Bp + (size_t)br * D + bcg * 16;

    float4 a0, a1, w0, w1, w2, w3;
    a0 = *(const float4*)(aptr);      a1 = *(const float4*)(aptr + 4);
    w0 = *(const float4*)(bptr);      w1 = *(const float4*)(bptr + 4);
    w2 = *(const float4*)(bptr + 8);  w3 = *(const float4*)(bptr + 12);

    float c0[4] = {0.f, 0.f, 0.f, 0.f};
    float c1[4] = {0.f, 0.f, 0.f, 0.f};

    for (int kt = 0; kt < 8; kt++) {
        int ka = acg * 8;
        As[ka + 0][ar] = a0.x; As[ka + 1][ar] = a0.y;
        As[ka + 2][ar] = a0.z; As[ka + 3][ar] = a0.w;
        As[ka + 4][ar] = a1.x; As[ka + 5][ar] = a1.y;
        As[ka + 6][ar] = a1.z; As[ka + 7][ar] = a1.w;
        int kb = bcg * 16;
        Ws[kb + 0][br] = w0.x;  Ws[kb + 1][br] = w0.y;
        Ws[kb + 2][br] = w0.z;  Ws[kb + 3][br] = w0.w;
        Ws[kb + 4][br] = w1.x;  Ws[kb + 5][br] = w1.y;
        Ws[kb + 6][br] = w1.z;  Ws[kb + 7][br] = w1.w;
        Ws[kb + 8][br] = w2.x;  Ws[kb + 9][br] = w2.y;
        Ws[kb + 10][br] = w2.z; Ws[kb + 11][br] = w2.w;
        Ws[kb + 12][br] = w3.x; Ws[kb + 13][br] = w3.y;
        Ws[kb + 14][br] = w3.z; Ws[kb + 15][br] = w3.w;
        __syncthreads();
        if (kt < 7) { // prefetch next K-tile while computing this one
            const float* ap = aptr + (kt + 1) * 64;
            const float* bp = bptr + (kt + 1) * 64;
            a0 = *(const float4*)(ap);     a1 = *(const float4*)(ap + 4);
            w0 = *(const float4*)(bp);     w1 = *(const float4*)(bp + 4);
            w2 = *(const float4*)(bp + 8); w3 = *(const float4*)(bp + 12);
        }
#pragma unroll 8
        for (int k = 0; k < 64; k++) {
            float2 av = *(const float2*)&As[k][ty * 2];
            float4 wv = *(const float4*)&Ws[k][tx * 4];
            c0[0] = fmaf(av.x, wv.x, c0[0]);
            c0[1] = fmaf(av.x, wv.y, c0[1]);
            c0[2] = fmaf(av.x, wv.z, c0[2]);
            c0[3] = fmaf(av.x, wv.w, c0[3]);
            c1[0] = fmaf(av.y, wv.x, c1[0]);
            c1[1] = fmaf(av.y, wv.y, c1[1]);
            c1[2] = fmaf(av.y, wv.z, c1[2]);
            c1[3] = fmaf(av.y, wv.w, c1[3]);
        }
        __syncthreads();
    }
    float4 o0 = {c0[0] * C2, c0[1] * C2, c0[2] * C2, c0[3] * C2};
    float4 o1 = {c1[0] * C2, c1[1] * C2, c1[2] * C2, c1[3] * C2};
    *(float4*)&out[(size_t)(ty * 2 + 0) * 256 + tx * 4] = o0;
    *(float4*)&out[(size_t)(ty * 2 + 1) * 256 + tx * 4] = o1;
}

// ---------------------------------------------------------------------------
// score_attn: per block = (b, 2 queries). 512 threads, 512 blocks (2/CU).
//  score(i,j) = Vsum + sum_p (-2 v[p]) * rcp(exp2(pq'[i,p]+pkT'[p,j]) + 1)
//  Vsum is constant -> dropped (softmax shift-invariant).
// Phase 1: thread = (jg in 128 -> 2 keys, h in 4 -> 64 p). Coalesced float2.
// Phase 2: softmax (threads 0..255 = key j), weights -> LDS + d_out.
// Phase 3: thread = (dg in 128 -> 4 d, jh in 4 -> 64 j), LDS combine.
// ---------------------------------------------------------------------------
__global__ __launch_bounds__(512)
void score_attn_kernel(const float* __restrict__ seq,
                       const float* __restrict__ pkT, const float* __restrict__ pq,
                       const float* __restrict__ v, const float* __restrict__ mask,
                       float* __restrict__ wout, float* __restrict__ attn) {
    __shared__ float pqs[2][P];       // 2 KB
    __shared__ float vs[P];           // 1 KB  (-2*v)
    __shared__ float part[4][2][S];   // 8 KB
    __shared__ float wsm[S][2];       // 2 KB
    __shared__ float p3[4][2][D];     // 16 KB
    __shared__ float redm[2][8], reds[2][8];

    int bid0 = blockIdx.x;
    int bid = (bid0 & 7) * 64 + (bid0 >> 3); // XCD swizzle (512 = 8*64)
    int b = bid >> 7;
    int i0 = (bid & 127) * 2;
    int tid = threadIdx.x;
    int lane = tid & 63, wid = tid >> 6;

    // stage pq' rows (2 x 256, contiguous) and v' = -2v
    if (tid < 256) {
        ((float2*)pqs)[tid] = ((const float2*)(pq + ((size_t)b * S + i0) * P))[tid];
    } else if (tid < 384) {
        int x = tid - 256;
        float2 vv = ((const float2*)v)[x];
        ((float2*)vs)[x] = make_float2(-2.f * vv.x, -2.f * vv.y);
    }
    __syncthreads();

    // phase 1: partial scores. j = 2*jg + {0,1}, p in [64h, 64h+64)
    {
        int jg = tid & 127, h = tid >> 7;
        const float2* kp = (const float2*)(pkT + (size_t)b * P * S);
        float acc00 = 0.f, acc01 = 0.f, acc10 = 0.f, acc11 = 0.f;
        int pbase = h * 64;
#pragma unroll 4
        for (int pp = 0; pp < 64; pp += 4) {
            int p = pbase + pp;
            float2 k0 = kp[(size_t)(p + 0) * 128 + jg];
            float2 k1 = kp[(size_t)(p + 1) * 128 + jg];
            float2 k2 = kp[(size_t)(p + 2) * 128 + jg];
            float2 k3 = kp[(size_t)(p + 3) * 128 + jg];
            float4 vv = *(const float4*)&vs[p];
            float4 q0 = *(const float4*)&pqs[0][p];
            float4 q1 = *(const float4*)&pqs[1][p];
#define TANH4(kv, vvv, qa, qb)                                     \
            {                                                      \
                float t00 = fast_exp2(kv.x + qa);                  \
                float t01 = fast_exp2(kv.y + qa);                  \
                float t10 = fast_exp2(kv.x + qb);                  \
                float t11 = fast_exp2(kv.y + qb);                  \
                acc00 = fmaf(vvv, fast_rcp(t00 + 1.f), acc00);     \
                acc01 = fmaf(vvv, fast_rcp(t01 + 1.f), acc01);     \
                acc10 = fmaf(vvv, fast_rcp(t10 + 1.f), acc10);     \
                acc11 = fmaf(vvv, fast_rcp(t11 + 1.f), acc11);     \
            }
            TANH4(k0, vv.x, q0.x, q1.x)
            TANH4(k1, vv.y, q0.y, q1.y)
            TANH4(k2, vv.z, q0.z, q1.z)
            TANH4(k3, vv.w, q0.w, q1.w)
#undef TANH4
        }
        int j0 = 2 * jg;
        part[h][0][j0] = acc00; part[h][0][j0 + 1] = acc01;
        part[h][1][j0] = acc10; part[h][1][j0 + 1] = acc11;
    }
    __syncthreads();

    // phase 2: softmax over keys (threads 0..255 = j)
    float s0 = -3.0e38f, s1 = -3.0e38f;
    if (tid < 256) {
        int j = tid;
        s0 = (part[0][0][j] + part[1][0][j]) + (part[2][0][j] + part[3][0][j]);
        s1 = (part[0][1][j] + part[1][1][j]) + (part[2][1][j] + part[3][1][j]);
        float km = mask[(size_t)b * S + j];
        if (!(km > 0.f)) { s0 = NEG_INF; s1 = NEG_INF; }
    }
    float m0 = s0, m1 = s1;
#pragma unroll
    for (int off = 32; off >= 1; off >>= 1) {
        m0 = fmaxf(m0, __shfl_xor(m0, off, 64));
        m1 = fmaxf(m1, __shfl_xor(m1, off, 64));
    }
    if (lane == 0) { redm[0][wid] = m0; redm[1][wid] = m1; }
    __syncthreads();
    m0 = fmaxf(fmaxf(redm[0][0], redm[0][1]), fmaxf(redm[0][2], redm[0][3]));
    m1 = fmaxf(fmaxf(redm[1][0], redm[1][1]), fmaxf(redm[1][2], redm[1][3]));
    float e0 = 0.f, e1 = 0.f;
    if (tid < 256) {
        e0 = fast_exp2((s0 - m0) * LOG2E);
        e1 = fast_exp2((s1 - m1) * LOG2E);
    }
    float t0 = e0, t1 = e1;
#pragma unroll
    for (int off = 32; off >= 1; off >>= 1) {
        t0 += __shfl_xor(t0, off, 64);
        t1 += __shfl_xor(t1, off, 64);
    }
    if (lane == 0) { reds[0][wid] = t0; reds[1][wid] = t1; }
    __syncthreads();
    float sum0 = (reds[0][0] + reds[0][1]) + (reds[0][2] + reds[0][3]);
    float sum1 = (reds[1][0] + reds[1][1]) + (reds[1][2] + reds[1][3]);
    if (tid < 256) {
        int j = tid;
        float qm0 = mask[(size_t)b * S + i0];
        float qm1 = mask[(size_t)b * S + i0 + 1];
        float w0 = e0 * fast_rcp(sum0) * qm0;
        float w1 = e1 * fast_rcp(sum1) * qm1;
        wsm[j][0] = w0; wsm[j][1] = w1;
        wout[((size_t)b * S + i0) * S + j] = w0;
        wout[((size_t)b * S + i0 + 1) * S + j] = w1;
    }
    __syncthreads();

    // phase 3: attn = w @ seq.  thread = (dg -> 4 d, jh -> 64 j)
    {
        int dg = tid & 127, jh = tid >> 7;
        int d0 = dg * 4;
        const float4* sp = (const float4*)(seq + (size_t)b * S * D);
        float4 A0 = {0.f, 0.f, 0.f, 0.f}, A1 = {0.f, 0.f, 0.f, 0.f};
#pragma unroll 4
        for (int jj = 0; jj < 64; jj++) {
            int j = jh * 64 + jj;
            float4 s4 = sp[(size_t)j * 128 + dg];
            float2 w = *(const float2*)&wsm[j][0];
            A0.x = fmaf(w.x, s4.x, A0.x); A0.y = fmaf(w.x, s4.y, A0.y);
            A0.z = fmaf(w.x, s4.z, A0.z); A0.w = fmaf(w.x, s4.w, A0.w);
            A1.x = fmaf(w.y, s4.x, A1.x); A1.y = fmaf(w.y, s4.y, A1.y);
            A1.z = fmaf(w.y, s4.z, A1.z); A1.w = fmaf(w.y, s4.w, A1.w);
        }
        *(float4*)&p3[jh][0][d0] = A0;
        *(float4*)&p3[jh][1][d0] = A1;
    }
    __syncthreads();
    {
        int d = tid;
        float r0 = (p3[0][0][d] + p3[1][0][d]) + (p3[2][0][d] + p3[3][0][d]);
        float r1 = (p3[0][1][d] + p3[1][1][d]) + (p3[2][1][d] + p3[3][1][d]);
        attn[((size_t)b * S + i0) * D + d] = r0;
        attn[((size_t)b * S + i0 + 1) * D + d] = r1;
    }
}

// ---------------------------------------------------------------------------
extern "C" void kernel_launch(void* const* d_in, const int* in_sizes, int n_in,
                              void* d_out, int out_size, void* d_ws, size_t ws_size,
                              hipStream_t stream) {
    const float* seq  = (const float*)d_in[0];
    const float* mask = (const float*)d_in[1];
    const float* W1   = (const float*)d_in[2];
    const float* W2   = (const float*)d_in[3];
    const float* v    = (const float*)d_in[4];

    float* attn = (float*)d_out;                 // [B,S,D]
    float* wout = attn + (size_t)B * S * D;      // [B,S,S]

    float* pq  = (float*)d_ws;                   // [B*S, P]  (scaled by C2)
    float* pkT = pq + (size_t)B * S * P;         // [B, P, S] (scaled by C2)

    proj_kernel<<<256, 256, 0, stream>>>(seq, W1, W2, pq, pkT);
    score_attn_kernel<<<B * (S / 2), 512, 0, stream>>>(seq, pkT, pq, v, mask,
                                                       wout, attn);
}

// Round 4
// 42.006 us; speedup vs baseline: 2.0458x; 1.0519x over previous
//
#include <hip/hip_runtime.h>

// Problem constants (fixed by setup_inputs): B=4, S=256, D=512, P=256
constexpr int B = 4;
constexpr int S = 256;
constexpr int D = 512;
constexpr int P = 256;
constexpr float NEG_INF = -1e9f;
constexpr float LOG2E = 1.4426950408889634f;
constexpr float C2 = 2.885390081777927f; // 2*log2(e):  exp2(C2*x) = e^{2x}

__device__ __forceinline__ float fast_exp2(float x) {
#if __has_builtin(__builtin_amdgcn_exp2f)
    return __builtin_amdgcn_exp2f(x);
#else
    return exp2f(x);
#endif
}

__device__ __forceinline__ float fast_rcp(float x) {
#if __has_builtin(__builtin_amdgcn_rcpf)
    return __builtin_amdgcn_rcpf(x);
#else
    return 1.0f / x;
#endif
}

// ---------------------------------------------------------------------------
// proj: acc[m][n] = sum_k A[m][k] * Brows[n][k];  out = exp2(C2 * acc)
//   bid <  128 : Eq  tiles  (A = seq rows, Brows = W2)   Eq[b*S+i][p]
//   bid >= 128 : EkT tiles  (A = W1 rows,  Brows = seq[b]) EkT[b][p][j]
// tile 32m x 64n, K-tile 64, 256 threads, thread-tile 2m x 4n, reg prefetch.
// ---------------------------------------------------------------------------
__global__ __launch_bounds__(256)
void proj_kernel(const float* __restrict__ seq,
                 const float* __restrict__ W1, const float* __restrict__ W2,
                 float* __restrict__ Eq, float* __restrict__ EkT) {
    __shared__ float As[64][34]; // [k][m]
    __shared__ float Ws[64][68]; // [k][n]

    int bid0 = blockIdx.x;
    int bid = (bid0 & 7) * 32 + (bid0 >> 3); // XCD-aware swizzle (256 = 8*32)

    const float* A;
    const float* Bp;
    float* out;
    if (bid < 128) { // Eq
        int mt = bid >> 2, nt = bid & 3;
        A = seq + (size_t)mt * 32 * D;
        Bp = W2 + (size_t)nt * 64 * D;
        out = Eq + (size_t)mt * 32 * 256 + nt * 64;
    } else {         // EkT
        int r = bid - 128;
        int b = r >> 5, t = r & 31;
        int mt = t >> 2, nt = t & 3;
        A = W1 + (size_t)mt * 32 * D;
        Bp = seq + ((size_t)b * S + nt * 64) * D;
        out = EkT + (size_t)b * P * S + (size_t)mt * 32 * 256 + nt * 64;
    }

    int tid = threadIdx.x;
    int tx = tid & 15, ty = tid >> 4;
    int ar = tid >> 3, acg = tid & 7;   // A stage: row, 8-float chunk
    int br = tid >> 2, bcg = tid & 3;   // B stage: row, 16-float chunk
    const float* aptr = A + (size_t)ar * D + acg * 8;
    const float* bptr = Bp + (size_t)br * D + bcg * 16;

    float4 a0, a1, w0, w1, w2, w3;
    a0 = *(const float4*)(aptr);      a1 = *(const float4*)(aptr + 4);
    w0 = *(const float4*)(bptr);      w1 = *(const float4*)(bptr + 4);
    w2 = *(const float4*)(bptr + 8);  w3 = *(const float4*)(bptr + 12);

    float c0[4] = {0.f, 0.f, 0.f, 0.f};
    float c1[4] = {0.f, 0.f, 0.f, 0.f};

    for (int kt = 0; kt < 8; kt++) {
        int ka = acg * 8;
        As[ka + 0][ar] = a0.x; As[ka + 1][ar] = a0.y;
        As[ka + 2][ar] = a0.z; As[ka + 3][ar] = a0.w;
        As[ka + 4][ar] = a1.x; As[ka + 5][ar] = a1.y;
        As[ka + 6][ar] = a1.z; As[ka + 7][ar] = a1.w;
        int kb = bcg * 16;
        Ws[kb + 0][br] = w0.x;  Ws[kb + 1][br] = w0.y;
        Ws[kb + 2][br] = w0.z;  Ws[kb + 3][br] = w0.w;
        Ws[kb + 4][br] = w1.x;  Ws[kb + 5][br] = w1.y;
        Ws[kb + 6][br] = w1.z;  Ws[kb + 7][br] = w1.w;
        Ws[kb + 8][br] = w2.x;  Ws[kb + 9][br] = w2.y;
        Ws[kb + 10][br] = w2.z; Ws[kb + 11][br] = w2.w;
        Ws[kb + 12][br] = w3.x; Ws[kb + 13][br] = w3.y;
        Ws[kb + 14][br] = w3.z; Ws[kb + 15][br] = w3.w;
        __syncthreads();
        if (kt < 7) { // prefetch next K-tile while computing this one
            const float* ap = aptr + (kt + 1) * 64;
            const float* bp = bptr + (kt + 1) * 64;
            a0 = *(const float4*)(ap);     a1 = *(const float4*)(ap + 4);
            w0 = *(const float4*)(bp);     w1 = *(const float4*)(bp + 4);
            w2 = *(const float4*)(bp + 8); w3 = *(const float4*)(bp + 12);
        }
#pragma unroll 8
        for (int k = 0; k < 64; k++) {
            float2 av = *(const float2*)&As[k][ty * 2];
            float4 wv = *(const float4*)&Ws[k][tx * 4];
            c0[0] = fmaf(av.x, wv.x, c0[0]);
            c0[1] = fmaf(av.x, wv.y, c0[1]);
            c0[2] = fmaf(av.x, wv.z, c0[2]);
            c0[3] = fmaf(av.x, wv.w, c0[3]);
            c1[0] = fmaf(av.y, wv.x, c1[0]);
            c1[1] = fmaf(av.y, wv.y, c1[1]);
            c1[2] = fmaf(av.y, wv.z, c1[2]);
            c1[3] = fmaf(av.y, wv.w, c1[3]);
        }
        __syncthreads();
    }
    float4 o0 = {fast_exp2(c0[0] * C2), fast_exp2(c0[1] * C2),
                 fast_exp2(c0[2] * C2), fast_exp2(c0[3] * C2)};
    float4 o1 = {fast_exp2(c1[0] * C2), fast_exp2(c1[1] * C2),
                 fast_exp2(c1[2] * C2), fast_exp2(c1[3] * C2)};
    *(float4*)&out[(size_t)(ty * 2 + 0) * 256 + tx * 4] = o0;
    *(float4*)&out[(size_t)(ty * 2 + 1) * 256 + tx * 4] = o1;
}

// ---------------------------------------------------------------------------
// score_attn: block = (b, 4 queries). 512 threads, 256 blocks.
//  score(i,j) = const + sum_p (-2 v[p]) * rcp(Eq[i,p]*EkT[p,j] + 1)
//  (const dropped: softmax shift-invariant).  2 VALU + 1 rcp per element.
// Phase 1: thread = (jg in 128 -> 2 keys, h in 4 -> 64 p). Coalesced float2.
// Phase 2: softmax (threads 0..255 = key j), weights -> LDS + d_out.
// Phase 3: thread = d (512 = D): attn = w @ seq, LDS-broadcast weights.
// ---------------------------------------------------------------------------
__global__ __launch_bounds__(512)
void score_attn_kernel(const float* __restrict__ seq,
                       const float* __restrict__ EkT, const float* __restrict__ Eq,
                       const float* __restrict__ v, const float* __restrict__ mask,
                       float* __restrict__ wout, float* __restrict__ attn) {
    __shared__ float Eqs[4][P];       // 4 KB
    __shared__ float vs[P];           // 1 KB  (-2*v)
    __shared__ float part[4][4][S];   // 16 KB [h][q][j]
    __shared__ float wsm[S][4];       // 4 KB
    __shared__ float redm[4][8], reds[4][8];

    int bid0 = blockIdx.x;
    int bid = (bid0 & 7) * 32 + (bid0 >> 3); // XCD swizzle (256 = 8*32)
    int b = bid >> 6;
    int i0 = (bid & 63) * 4;
    int tid = threadIdx.x;
    int lane = tid & 63, wid = tid >> 6;

    // stage Eq rows (4 x 256 contiguous floats) and v' = -2v
    ((float2*)Eqs)[tid] = ((const float2*)(Eq + ((size_t)b * S + i0) * P))[tid];
    if (tid < 128) {
        float2 vv = ((const float2*)v)[tid];
        ((float2*)vs)[tid] = make_float2(-2.f * vv.x, -2.f * vv.y);
    }
    __syncthreads();

    // phase 1: partial scores. j = 2*jg + {0,1}, p in [64h, 64h+64)
    {
        int jg = tid & 127, h = tid >> 7;
        const float2* kp = (const float2*)(EkT + (size_t)b * P * S) + jg;
        int pbase = h * 64;
        float acc[2][4] = {{0.f, 0.f, 0.f, 0.f}, {0.f, 0.f, 0.f, 0.f}};
        for (int pp = 0; pp < 64; pp += 4) {
            int p = pbase + pp;
            float2 kk[4];
#pragma unroll
            for (int t = 0; t < 4; t++) kk[t] = kp[(size_t)(p + t) * 128];
            float4 vv4 = *(const float4*)&vs[p];
            float vvv[4] = {vv4.x, vv4.y, vv4.z, vv4.w};
#pragma unroll
            for (int q = 0; q < 4; q++) {
                float4 e4 = *(const float4*)&Eqs[q][p];
                float ee[4] = {e4.x, e4.y, e4.z, e4.w};
#pragma unroll
                for (int t = 0; t < 4; t++) {
                    float t0 = fmaf(kk[t].x, ee[t], 1.f);
                    float t1 = fmaf(kk[t].y, ee[t], 1.f);
                    acc[0][q] = fmaf(vvv[t], fast_rcp(t0), acc[0][q]);
                    acc[1][q] = fmaf(vvv[t], fast_rcp(t1), acc[1][q]);
                }
            }
        }
#pragma unroll
        for (int q = 0; q < 4; q++)
            ((float2*)&part[h][q][0])[jg] = make_float2(acc[0][q], acc[1][q]);
    }
    __syncthreads();

    // phase 2: softmax over keys (threads 0..255 = j)
    float s[4], e[4] = {0.f, 0.f, 0.f, 0.f};
    if (tid < 256) {
        int j = tid;
        float km = mask[(size_t)b * S + j];
#pragma unroll
        for (int q = 0; q < 4; q++) {
            float sv = (part[0][q][j] + part[1][q][j]) +
                       (part[2][q][j] + part[3][q][j]);
            s[q] = (km > 0.f) ? sv : NEG_INF;
            float mm = s[q];
#pragma unroll
            for (int off = 32; off >= 1; off >>= 1)
                mm = fmaxf(mm, __shfl_xor(mm, off, 64));
            if (lane == 0) redm[q][wid] = mm;
        }
    }
    __syncthreads();
    if (tid < 256) {
#pragma unroll
        for (int q = 0; q < 4; q++) {
            float mm = fmaxf(fmaxf(redm[q][0], redm[q][1]),
                             fmaxf(redm[q][2], redm[q][3]));
            float ee = fast_exp2((s[q] - mm) * LOG2E);
            e[q] = ee;
            float ss = ee;
#pragma unroll
            for (int off = 32; off >= 1; off >>= 1)
                ss += __shfl_xor(ss, off, 64);
            if (lane == 0) reds[q][wid] = ss;
        }
    }
    __syncthreads();
    if (tid < 256) {
        int j = tid;
#pragma unroll
        for (int q = 0; q < 4; q++) {
            float ssum = (reds[q][0] + reds[q][1]) + (reds[q][2] + reds[q][3]);
            float qm = mask[(size_t)b * S + i0 + q];
            float w = e[q] * fast_rcp(ssum) * qm;
            wsm[j][q] = w;
            wout[((size_t)b * S + i0 + q) * S + j] = w;
        }
    }
    __syncthreads();

    // phase 3: attn[b, i0+q, d] = sum_j w[j][q] * seq[b, j, d]; thread = d
    {
        int d = tid;
        const float* sp = seq + (size_t)b * S * D + d;
        float a0 = 0.f, a1 = 0.f, a2 = 0.f, a3 = 0.f;
#pragma unroll 8
        for (int j = 0; j < S; j++) {
            float sv = sp[(size_t)j * D];
            float4 w4 = *(const float4*)&wsm[j][0];
            a0 = fmaf(w4.x, sv, a0);
            a1 = fmaf(w4.y, sv, a1);
            a2 = fmaf(w4.z, sv, a2);
            a3 = fmaf(w4.w, sv, a3);
        }
        attn[((size_t)b * S + i0 + 0) * D + d] = a0;
        attn[((size_t)b * S + i0 + 1) * D + d] = a1;
        attn[((size_t)b * S + i0 + 2) * D + d] = a2;
        attn[((size_t)b * S + i0 + 3) * D + d] = a3;
    }
}

// ---------------------------------------------------------------------------
extern "C" void kernel_launch(void* const* d_in, const int* in_sizes, int n_in,
                              void* d_out, int out_size, void* d_ws, size_t ws_size,
                              hipStream_t stream) {
    const float* seq  = (const float*)d_in[0];
    const float* mask = (const float*)d_in[1];
    const float* W1   = (const float*)d_in[2];
    const float* W2   = (const float*)d_in[3];
    const float* v    = (const float*)d_in[4];

    float* attn = (float*)d_out;                 // [B,S,D]
    float* wout = attn + (size_t)B * S * D;      // [B,S,S]

    float* Eq  = (float*)d_ws;                   // [B*S, P]  = exp2(C2*pq)
    float* EkT = Eq + (size_t)B * S * P;         // [B, P, S] = exp2(C2*pk)^T

    proj_kernel<<<256, 256, 0, stream>>>(seq, W1, W2, Eq, EkT);
    score_attn_kernel<<<B * (S / 4), 512, 0, stream>>>(seq, EkT, Eq, v, mask,
                                                       wout, attn);
}

// Round 5
// 41.286 us; speedup vs baseline: 2.0815x; 1.0174x over previous
//
#include <hip/hip_runtime.h>

// Problem constants (fixed by setup_inputs): B=4, S=256, D=512, P=256
constexpr int B = 4;
constexpr int S = 256;
constexpr int D = 512;
constexpr int P = 256;
constexpr float NEG_INF = -1e9f;
constexpr float LOG2E = 1.4426950408889634f;
constexpr float C2 = 2.885390081777927f; // 2*log2(e):  exp2(C2*x) = e^{2x}

__device__ __forceinline__ float fast_exp2(float x) {
#if __has_builtin(__builtin_amdgcn_exp2f)
    return __builtin_amdgcn_exp2f(x);
#else
    return exp2f(x);
#endif
}

__device__ __forceinline__ float fast_rcp(float x) {
#if __has_builtin(__builtin_amdgcn_rcpf)
    return __builtin_amdgcn_rcpf(x);
#else
    return 1.0f / x;
#endif
}

// ---------------------------------------------------------------------------
// proj: acc[m][n] = sum_k A[m][k] * Brows[n][k];  out = exp2(C2 * acc)
// (unchanged from round 4 for attribution)
// ---------------------------------------------------------------------------
__global__ __launch_bounds__(256)
void proj_kernel(const float* __restrict__ seq,
                 const float* __restrict__ W1, const float* __restrict__ W2,
                 float* __restrict__ Eq, float* __restrict__ EkT) {
    __shared__ float As[64][34]; // [k][m]
    __shared__ float Ws[64][68]; // [k][n]

    int bid0 = blockIdx.x;
    int bid = (bid0 & 7) * 32 + (bid0 >> 3); // XCD-aware swizzle (256 = 8*32)

    const float* A;
    const float* Bp;
    float* out;
    if (bid < 128) { // Eq
        int mt = bid >> 2, nt = bid & 3;
        A = seq + (size_t)mt * 32 * D;
        Bp = W2 + (size_t)nt * 64 * D;
        out = Eq + (size_t)mt * 32 * 256 + nt * 64;
    } else {         // EkT
        int r = bid - 128;
        int b = r >> 5, t = r & 31;
        int mt = t >> 2, nt = t & 3;
        A = W1 + (size_t)mt * 32 * D;
        Bp = seq + ((size_t)b * S + nt * 64) * D;
        out = EkT + (size_t)b * P * S + (size_t)mt * 32 * 256 + nt * 64;
    }

    int tid = threadIdx.x;
    int tx = tid & 15, ty = tid >> 4;
    int ar = tid >> 3, acg = tid & 7;
    int br = tid >> 2, bcg = tid & 3;
    const float* aptr = A + (size_t)ar * D + acg * 8;
    const float* bptr = Bp + (size_t)br * D + bcg * 16;

    float4 a0, a1, w0, w1, w2, w3;
    a0 = *(const float4*)(aptr);      a1 = *(const float4*)(aptr + 4);
    w0 = *(const float4*)(bptr);      w1 = *(const float4*)(bptr + 4);
    w2 = *(const float4*)(bptr + 8);  w3 = *(const float4*)(bptr + 12);

    float c0[4] = {0.f, 0.f, 0.f, 0.f};
    float c1[4] = {0.f, 0.f, 0.f, 0.f};

    for (int kt = 0; kt < 8; kt++) {
        int ka = acg * 8;
        As[ka + 0][ar] = a0.x; As[ka + 1][ar] = a0.y;
        As[ka + 2][ar] = a0.z; As[ka + 3][ar] = a0.w;
        As[ka + 4][ar] = a1.x; As[ka + 5][ar] = a1.y;
        As[ka + 6][ar] = a1.z; As[ka + 7][ar] = a1.w;
        int kb = bcg * 16;
        Ws[kb + 0][br] = w0.x;  Ws[kb + 1][br] = w0.y;
        Ws[kb + 2][br] = w0.z;  Ws[kb + 3][br] = w0.w;
        Ws[kb + 4][br] = w1.x;  Ws[kb + 5][br] = w1.y;
        Ws[kb + 6][br] = w1.z;  Ws[kb + 7][br] = w1.w;
        Ws[kb + 8][br] = w2.x;  Ws[kb + 9][br] = w2.y;
        Ws[kb + 10][br] = w2.z; Ws[kb + 11][br] = w2.w;
        Ws[kb + 12][br] = w3.x; Ws[kb + 13][br] = w3.y;
        Ws[kb + 14][br] = w3.z; Ws[kb + 15][br] = w3.w;
        __syncthreads();
        if (kt < 7) {
            const float* ap = aptr + (kt + 1) * 64;
            const float* bp = bptr + (kt + 1) * 64;
            a0 = *(const float4*)(ap);     a1 = *(const float4*)(ap + 4);
            w0 = *(const float4*)(bp);     w1 = *(const float4*)(bp + 4);
            w2 = *(const float4*)(bp + 8); w3 = *(const float4*)(bp + 12);
        }
#pragma unroll 8
        for (int k = 0; k < 64; k++) {
            float2 av = *(const float2*)&As[k][ty * 2];
            float4 wv = *(const float4*)&Ws[k][tx * 4];
            c0[0] = fmaf(av.x, wv.x, c0[0]);
            c0[1] = fmaf(av.x, wv.y, c0[1]);
            c0[2] = fmaf(av.x, wv.z, c0[2]);
            c0[3] = fmaf(av.x, wv.w, c0[3]);
            c1[0] = fmaf(av.y, wv.x, c1[0]);
            c1[1] = fmaf(av.y, wv.y, c1[1]);
            c1[2] = fmaf(av.y, wv.z, c1[2]);
            c1[3] = fmaf(av.y, wv.w, c1[3]);
        }
        __syncthreads();
    }
    float4 o0 = {fast_exp2(c0[0] * C2), fast_exp2(c0[1] * C2),
                 fast_exp2(c0[2] * C2), fast_exp2(c0[3] * C2)};
    float4 o1 = {fast_exp2(c1[0] * C2), fast_exp2(c1[1] * C2),
                 fast_exp2(c1[2] * C2), fast_exp2(c1[3] * C2)};
    *(float4*)&out[(size_t)(ty * 2 + 0) * 256 + tx * 4] = o0;
    *(float4*)&out[(size_t)(ty * 2 + 1) * 256 + tx * 4] = o1;
}

// ---------------------------------------------------------------------------
// score_attn v5: block = (b, 4 queries), 512 threads, 256 blocks.
// Phase 1: Ek staged in LDS chunks of 32 p (reg-double-buffered; loads for
//          chunk c+2 issued under chunk c's compute). thread = (j, p-half).
// Phase 2: softmax (threads 0..255 = key j) -> wsm + wout.
// Phase 3: thread = (4-d group, j-quarter): float4 seq loads, LDS combine.
// ---------------------------------------------------------------------------
__global__ __launch_bounds__(512)
void score_attn_kernel(const float* __restrict__ seq,
                       const float* __restrict__ EkT, const float* __restrict__ Eq,
                       const float* __restrict__ v, const float* __restrict__ mask,
                       float* __restrict__ wout, float* __restrict__ attn) {
    __shared__ float Eqs[4][P];        // 4 KB
    __shared__ float vsm[P];           // 1 KB  (-2*v)
    __shared__ float ekb[2][32][256];  // 64 KB double-buffered Ek chunks
    __shared__ float part[2][4][S];    // 8 KB  [h][q][j]
    __shared__ float wsm[S][4];        // 4 KB
    __shared__ float p3[4][4][D];      // 32 KB [jh][q][d]
    __shared__ float redm[4][8], reds[4][8];

    int bid0 = blockIdx.x;
    int bid = (bid0 & 7) * 32 + (bid0 >> 3); // XCD swizzle (256 = 8*32)
    int b = bid >> 6;
    int i0 = (bid & 63) * 4;
    int tid = threadIdx.x;
    int lane = tid & 63, wid = tid >> 6;

    const float* ekbase = EkT + (size_t)b * P * S; // 65536 floats, chunk = 8192

    float4 r0, r1, r2, r3;
#define LOADC(c)                                                       \
    {                                                                  \
        const float4* sp_ = (const float4*)(ekbase + (c) * 8192);      \
        r0 = sp_[tid]; r1 = sp_[tid + 512];                            \
        r2 = sp_[tid + 1024]; r3 = sp_[tid + 1536];                    \
    }
#define WRITEC(bf)                                                     \
    {                                                                  \
        float4* dp_ = (float4*)&ekb[bf][0][0];                         \
        dp_[tid] = r0; dp_[tid + 512] = r1;                            \
        dp_[tid + 1024] = r2; dp_[tid + 1536] = r3;                    \
    }

    LOADC(0);
    // stage Eq rows (4 x 256 contiguous) and v' = -2v
    ((float2*)Eqs)[tid] = ((const float2*)(Eq + ((size_t)b * S + i0) * P))[tid];
    if (tid < 128) {
        float2 vv = ((const float2*)v)[tid];
        ((float2*)vsm)[tid] = make_float2(-2.f * vv.x, -2.f * vv.y);
    }
    WRITEC(0);
    LOADC(1);
    __syncthreads();

    // phase 1
    int j = tid & 255, h = tid >> 8;
    float acc[4] = {0.f, 0.f, 0.f, 0.f};
    for (int c = 0; c < 8; c++) {
        int cur = c & 1;
        int pl0 = h * 16;
        int pg0 = c * 32 + pl0;
#pragma unroll
        for (int t = 0; t < 4; t++) {
            int pl = pl0 + t * 4, pg = pg0 + t * 4;
            float e0 = ekb[cur][pl + 0][j];
            float e1 = ekb[cur][pl + 1][j];
            float e2 = ekb[cur][pl + 2][j];
            float e3 = ekb[cur][pl + 3][j];
            float4 vv = *(const float4*)&vsm[pg];
#pragma unroll
            for (int q = 0; q < 4; q++) {
                float4 eq = *(const float4*)&Eqs[q][pg];
                acc[q] = fmaf(vv.x, fast_rcp(fmaf(e0, eq.x, 1.f)), acc[q]);
                acc[q] = fmaf(vv.y, fast_rcp(fmaf(e1, eq.y, 1.f)), acc[q]);
                acc[q] = fmaf(vv.z, fast_rcp(fmaf(e2, eq.z, 1.f)), acc[q]);
                acc[q] = fmaf(vv.w, fast_rcp(fmaf(e3, eq.w, 1.f)), acc[q]);
            }
        }
        if (c < 7) { WRITEC(cur ^ 1); }
        if (c < 6) { LOADC(c + 2); }
        __syncthreads();
    }
#undef LOADC
#undef WRITEC
#pragma unroll
    for (int q = 0; q < 4; q++) part[h][q][j] = acc[q];
    __syncthreads();

    // phase 2: softmax over keys (threads 0..255 = j)
    float s[4], e[4] = {0.f, 0.f, 0.f, 0.f};
    if (tid < 256) {
        float km = mask[(size_t)b * S + j];
#pragma unroll
        for (int q = 0; q < 4; q++) {
            float sv = part[0][q][j] + part[1][q][j];
            s[q] = (km > 0.f) ? sv : NEG_INF;
            float mm = s[q];
#pragma unroll
            for (int off = 32; off >= 1; off >>= 1)
                mm = fmaxf(mm, __shfl_xor(mm, off, 64));
            if (lane == 0) redm[q][wid] = mm;
        }
    }
    __syncthreads();
    if (tid < 256) {
#pragma unroll
        for (int q = 0; q < 4; q++) {
            float mm = fmaxf(fmaxf(redm[q][0], redm[q][1]),
                             fmaxf(redm[q][2], redm[q][3]));
            float ee = fast_exp2((s[q] - mm) * LOG2E);
            e[q] = ee;
            float ss = ee;
#pragma unroll
            for (int off = 32; off >= 1; off >>= 1)
                ss += __shfl_xor(ss, off, 64);
            if (lane == 0) reds[q][wid] = ss;
        }
    }
    __syncthreads();
    if (tid < 256) {
#pragma unroll
        for (int q = 0; q < 4; q++) {
            float ssum = (reds[q][0] + reds[q][1]) + (reds[q][2] + reds[q][3]);
            float qm = mask[(size_t)b * S + i0 + q];
            float w = e[q] * fast_rcp(ssum) * qm;
            wsm[j][q] = w;
            wout[((size_t)b * S + i0 + q) * S + j] = w;
        }
    }
    __syncthreads();

    // phase 3: attn = w @ seq. thread = (dg -> 4 d, jh -> 64 j), float4 loads.
    {
        int dg = tid & 127, jh = tid >> 7;
        int d0 = dg * 4;
        const float4* sp = (const float4*)(seq + (size_t)b * S * D);
        float4 A0 = {0.f, 0.f, 0.f, 0.f}, A1 = {0.f, 0.f, 0.f, 0.f};
        float4 A2 = {0.f, 0.f, 0.f, 0.f}, A3 = {0.f, 0.f, 0.f, 0.f};
#pragma unroll 4
        for (int jj = 0; jj < 64; jj++) {
            int jx = jh * 64 + jj;
            float4 s4 = sp[(size_t)jx * 128 + dg];
            float4 w4 = *(const float4*)&wsm[jx][0];
            A0.x = fmaf(w4.x, s4.x, A0.x); A0.y = fmaf(w4.x, s4.y, A0.y);
            A0.z = fmaf(w4.x, s4.z, A0.z); A0.w = fmaf(w4.x, s4.w, A0.w);
            A1.x = fmaf(w4.y, s4.x, A1.x); A1.y = fmaf(w4.y, s4.y, A1.y);
            A1.z = fmaf(w4.y, s4.z, A1.z); A1.w = fmaf(w4.y, s4.w, A1.w);
            A2.x = fmaf(w4.z, s4.x, A2.x); A2.y = fmaf(w4.z, s4.y, A2.y);
            A2.z = fmaf(w4.z, s4.z, A2.z); A2.w = fmaf(w4.z, s4.w, A2.w);
            A3.x = fmaf(w4.w, s4.x, A3.x); A3.y = fmaf(w4.w, s4.y, A3.y);
            A3.z = fmaf(w4.w, s4.z, A3.z); A3.w = fmaf(w4.w, s4.w, A3.w);
        }
        *(float4*)&p3[jh][0][d0] = A0;
        *(float4*)&p3[jh][1][d0] = A1;
        *(float4*)&p3[jh][2][d0] = A2;
        *(float4*)&p3[jh][3][d0] = A3;
    }
    __syncthreads();
    {
        int d = tid;
#pragma unroll
        for (int q = 0; q < 4; q++) {
            float r = (p3[0][q][d] + p3[1][q][d]) + (p3[2][q][d] + p3[3][q][d]);
            attn[((size_t)b * S + i0 + q) * D + d] = r;
        }
    }
}

// ---------------------------------------------------------------------------
extern "C" void kernel_launch(void* const* d_in, const int* in_sizes, int n_in,
                              void* d_out, int out_size, void* d_ws, size_t ws_size,
                              hipStream_t stream) {
    const float* seq  = (const float*)d_in[0];
    const float* mask = (const float*)d_in[1];
    const float* W1   = (const float*)d_in[2];
    const float* W2   = (const float*)d_in[3];
    const float* v    = (const float*)d_in[4];

    float* attn = (float*)d_out;                 // [B,S,D]
    float* wout = attn + (size_t)B * S * D;      // [B,S,S]

    float* Eq  = (float*)d_ws;                   // [B*S, P]  = exp2(C2*pq)
    float* EkT = Eq + (size_t)B * S * P;         // [B, P, S] = exp2(C2*pk)^T

    proj_kernel<<<256, 256, 0, stream>>>(seq, W1, W2, Eq, EkT);
    score_attn_kernel<<<B * (S / 4), 512, 0, stream>>>(seq, EkT, Eq, v, mask,
                                                       wout, attn);
}